// Round 14
// baseline (1309.756 us; speedup 1.0000x reference)
//
#include <hip/hip_runtime.h>

// Seq2Seq LSTM (enc 512 + dec 256 steps), H=50, B=2048, in/out dim 1.
//
// Round-25: r24 (MB=1, 1 cell/lane, barrier-free 1-wave blocks) with
// __launch_bounds__(64,1). Diagnosis r23/r24: launch_bounds(...,2) caps
// the UNIFIED gfx950 reg file at 256/wave; compiler split 128 arch + 128
// acc, but arch demand (~128 weight VGPRs + ~60 act) -> ~50 regs spilled
// per step (WRITE_SIZE 55-137MB), burying the chain in scratch latency.
// r20 (best, 468us) used (64,1): 160 VGPR + AGPRs, zero spill.
// This round: cap 512 -> no spill; grid 2048 blocks exactly fills
// 256CU x 4SIMD x 2, so if total regs land <=256 (r20 did) the HW
// co-schedules 2 independent waves/SIMD WITHOUT the artificial cap --
// testing the pipe-overlap theory for free. Two stacked gains:
//  (1) 1 cell/lane act tail (~45 ops vs r20's ~90): chain 1463 -> ~1310.
//  (2) if co-resident: wave B's 32 MFMAs (515cy pipe) fill wave A's
//      ~800cy act/DS window -> step ~1050-1150.
// Per-wave structure (r24): MB=1, 32 MFMA/step, h identity layout,
// reads 2xb128, writes 2xb16, in-lane fc + 64-lane butterfly, direct y
// store, no __syncthreads anywhere. [rule-#20-safe: static indices,
// runtime ugroup select via 2-stage ternary -> v_cndmask]
// Math identical to r20/r23/r24 (absmax 4.88e-4): fp16 weights (rel
// 2^-11), fp16-split h (h=h0+h1) via A-rows (split=m&1, 8x dup,
// D sums = acc[0]+acc[1]), L2E folded, g-gate doubled -> tanh via sigm.
//
// Fragment maps (verified r10-r24): A[m=lane&15][k=(lane>>4)*8+j],
// B[n=lane&15][k=kt*32+(lane>>4)*8+j], D col=lane&15, row=4*(lane>>4)+reg.

#define HID 50
#define SEQ 512
#define TGT 256
#define L2E 1.44269504088896341f

typedef __attribute__((ext_vector_type(8))) _Float16 half8;
typedef __attribute__((ext_vector_type(4))) float f32x4;

#define MFMA16(A, B, C) __builtin_amdgcn_mfma_f32_16x16x32_f16((A), (B), (C), 0, 0, 0)

// One LSTM step for this wave's batch. 1 cell/lane. Reads h from hs[IB],
// writes h' to hs[OB]. XV enters at the sum stage (post-MFMA -> decoder
// feedback off the gemv path). Updates cc; defines hv.
#define GSTEP(XV, IB, OB)                                                   \
    {                                                                       \
        const _Float16* hp_ = &hs[IB][sA][0];                               \
        half8 a0 = *(const half8*)(hp_ + kg * 8);        /* k 0..31  */     \
        half8 a1 = *(const half8*)(hp_ + 32 + kg * 8);   /* k 32..63 */     \
        f32x4 acc[16];                                                      \
        _Pragma("unroll")                                                   \
        for (int j = 0; j < 16; ++j) {                                      \
            f32x4 z = {0.0f, 0.0f, 0.0f, 0.0f};                             \
            z = MFMA16(a0, Bw[j][0], z);                                    \
            z = MFMA16(a1, Bw[j][1], z);                                    \
            acc[j] = z;                                                     \
        }                                                                   \
        float sums[16];                                                     \
        _Pragma("unroll")                                                   \
        for (int j = 0; j < 16; ++j)                                        \
            sums[j] = acc[j][0] + acc[j][1];      /* s0-row + s1-row */     \
        float xv_ = (XV);                                                   \
        float sm[4], R_[4];                                                 \
        _Pragma("unroll")                                                   \
        for (int g = 0; g < 4; ++g) {            /* select ug = kg */       \
            float s01 = (kg & 1) ? sums[g * 4 + 1] : sums[g * 4 + 0];       \
            float s23 = (kg & 1) ? sums[g * 4 + 3] : sums[g * 4 + 2];       \
            float sg  = (kg & 2) ? s23 : s01;                               \
            sm[g] = sg + fmaf(wx[g], xv_, bb[g]);                           \
        }                                                                   \
        _Pragma("unroll")                                                   \
        for (int g = 0; g < 4; ++g)                                         \
            R_[g] = __builtin_amdgcn_rcpf(1.0f +                            \
                        __builtin_amdgcn_exp2f(-sm[g]));                    \
        float vg = fmaf(2.0f, R_[2], -1.0f);     /* tanh via sigm */        \
        cc = fmaf(R_[1], cc, R_[0] * vg);                                   \
        float r2 = __builtin_amdgcn_rcpf(1.0f +                             \
                       __builtin_amdgcn_exp2f(-2.0f * L2E * cc));           \
        hv = R_[3] * fmaf(2.0f, r2, -1.0f);                                 \
        _Float16 q0 = (_Float16)hv;                                         \
        _Float16 q1 = (_Float16)(hv - (float)q0);                           \
        hs[OB][0][u] = q0;                        /* split0 */              \
        hs[OB][1][u] = q1;                        /* split1 */              \
    }

// Decoder step: GSTEP + in-lane fc + 64-lane butterfly; direct y store.
#define DSTEP(T, IB, OB)                                                    \
    {                                                                       \
        GSTEP(xc, IB, OB)                                                   \
        float p = fcw * hv;                                                 \
        p += __shfl_xor(p, 1, 64);                                          \
        p += __shfl_xor(p, 2, 64);                                          \
        p += __shfl_xor(p, 4, 64);                                          \
        p += __shfl_xor(p, 8, 64);                                          \
        p += __shfl_xor(p, 16, 64);                                         \
        p += __shfl_xor(p, 32, 64);                                         \
        float y = p + fb;                                                   \
        if (lane == 0) out[(size_t)b * TGT + (T)] = y;                      \
        xc = y;                                                             \
    }

extern "C" __global__ void __launch_bounds__(64, 1)
seq2seq_kernel(const float* __restrict__ src,
               const float* __restrict__ eWih, const float* __restrict__ eWhh,
               const float* __restrict__ eBih, const float* __restrict__ eBhh,
               const float* __restrict__ dWih, const float* __restrict__ dWhh,
               const float* __restrict__ dBih, const float* __restrict__ dBhh,
               const float* __restrict__ fcW, const float* __restrict__ fcB,
               float* __restrict__ out) {
    const int lane = threadIdx.x & 63;
    const int c    = lane & 15;          // D col / A row m
    const int kg   = lane >> 4;          // A/B k-octet; selects ugroup
    const int sA   = c & 1;              // A-row m -> h split (m&1)
    const int u    = kg * 16 + c;        // this lane's unit
    const int b    = blockIdx.x;         // this wave's batch

    // hs[buf][split][64 units]; single wave -> no barrier ever
    __shared__ __align__(16) _Float16 hs[2][2][64];
    __shared__ __align__(16) float srcT[SEQ];

    for (int i = lane; i < 2 * 2 * 64 / 2; i += 64) ((int*)hs)[i] = 0;
    for (int i = lane; i < SEQ; i += 64)
        srcT[i] = src[(size_t)b * SEQ + i];

    half8 Bw[16][2];                     // [tile=(g*4+ug)][kt] fp16 weights
    float wx[4], bb[4];                  // this cell's x-weights / bias
    float cc = 0.0f, hv;

    auto loadW = [&](const float* Wih, const float* Whh,
                     const float* Bih, const float* Bhh) {
#pragma unroll
        for (int j = 0; j < 16; ++j) {
            const int g  = j >> 2, ug = j & 3;             // tile=(gate,ug)
            const int uo = ug * 16 + c;                    // output unit
            const bool uv = (uo < HID);
            const float sc = (g == 2) ? 2.0f * L2E : L2E;  // tanh fold
            const int row = g * HID + (uv ? uo : 0);       // PyTorch g*50+u
#pragma unroll
            for (int kt = 0; kt < 2; ++kt) {
                half8 s0;
#pragma unroll
                for (int jj = 0; jj < 8; ++jj) {
                    int k = kt * 32 + kg * 8 + jj;         // pos = unit
                    float wv = (uv && k < HID)
                             ? Whh[(size_t)row * HID + k] * sc : 0.0f;
                    s0[jj] = (_Float16)wv;
                }
                Bw[j][kt] = s0;
            }
        }
#pragma unroll
        for (int g = 0; g < 4; ++g) {                      // my cell u
            const bool uv = (u < HID);
            const float sc = (g == 2) ? 2.0f * L2E : L2E;
            const int row = g * HID + (uv ? u : 0);
            wx[g] = uv ? Wih[row] * sc : 0.0f;
            bb[g] = uv ? (Bih[row] + Bhh[row]) * sc : 0.0f;
        }
    };

    // ---------------- encoder: 512 steps (x2 unroll, h dbuf) -------------
    loadW(eWih, eWhh, eBih, eBhh);
    if (b & 1) __builtin_amdgcn_s_sleep(7);    // anti-phase nudge (cheap)
    for (int t = 0; t < SEQ; t += 2) {
        float2 xp = *(const float2*)&srcT[t];
        { GSTEP(xp.x, 0, 1) }
        { GSTEP(xp.y, 1, 0) }
    }
    // h(512) in buf 0; cc persists in registers

    // ---------------- decoder: 256 steps (x2 unroll) ---------------------
    loadW(dWih, dWhh, dBih, dBhh);
    const float fcw = (u < HID) ? fcW[u] : 0.0f;
    const float fb  = fcB[0];
    float xc = 0.0f;                     // decoder_input = zeros
    for (int t = 0; t < TGT; t += 2) {
        DSTEP(t,     0, 1)
        DSTEP(t + 1, 1, 0)
    }
}

extern "C" void kernel_launch(void* const* d_in, const int* in_sizes, int n_in,
                              void* d_out, int out_size, void* d_ws, size_t ws_size,
                              hipStream_t stream) {
    const float* src  = (const float*)d_in[0];
    const float* eWih = (const float*)d_in[1];
    const float* eWhh = (const float*)d_in[2];
    const float* eBih = (const float*)d_in[3];
    const float* eBhh = (const float*)d_in[4];
    const float* dWih = (const float*)d_in[5];
    const float* dWhh = (const float*)d_in[6];
    const float* dBih = (const float*)d_in[7];
    const float* dBhh = (const float*)d_in[8];
    const float* fcW  = (const float*)d_in[9];
    const float* fcB  = (const float*)d_in[10];
    float* out = (float*)d_out;

    const int B = in_sizes[0] / SEQ;     // 2048
    seq2seq_kernel<<<B, 64, 0, stream>>>(src, eWih, eWhh, eBih, eBhh,
                                         dWih, dWhh, dBih, dBhh,
                                         fcW, fcB, out);
}

// Round 16
// 501.467 us; speedup vs baseline: 2.6119x; 2.6119x over previous
//
#include <hip/hip_runtime.h>

// Seq2Seq LSTM (enc 512 + dec 256 steps), H=50, B=2048, in/out dim 1.
//
// Round-26 (resubmit; r26 bench was an infra failure, never ran):
// CONSOLIDATION on r20 (best: 468us dispatch), one chain trim.
// r23/r24/r25 closed the co-residency arc: weight-resident waves need
// >256 unified regs (VGPR 164 + AGPR acc/operands) -> 1 wave/SIMD always;
// 2-wave overlap is structurally impossible. r20's 1463cy step = ds ~180
// + MFMA pipe 541 (floor for 32 MFMA) + act ~300 + issue. The one clean
// remaining trim: HOIST THE X-TERM. sm = sel + fmaf(wx,x,bb) put a
// dependent fmaf after the pipe; but wx*x+bb is h-independent (encoder x
// from srcT; decoder x = y(t), known ~800cy early). Precompute ib[8]
// early; tail becomes sel + ib (1 add); the 8 fmafs issue in the pipe/
// read shadow. Also removes the decoder POSTX special case.
//
// Structure (r20): 1 wave = 1 block = 2 batches, no __syncthreads.
// A-rows m = b*8 + dup*2 + s (4x dup); lane (c,kg) owns cells
// (batch kg>>1, units {32*(kg&1)+c, +16}). 32 MFMA/step (16 tiles x 2 kt).
// Split combine = static sums + ternary on ugp (rule-#20-safe).
// Grid 1024 = 1 wave/SIMD. Position perm: pos p <-> unit
// us = 32*(d>>4)+(d&15)+16*e, d=p>>1, e=p&1; producer writes one b32/split
// at p0=32*(kg&1)+2c; weights k-permuted at load. fp16 weights (rel 2^-11),
// fp16-split h, L2E folded (g-gate doubled -> tanh via sigm). Stage-major
// activation.

#define HID 50
#define SEQ 512
#define TGT 256
#define MB  2
#define NT  16                   // 4 gates x 4 unit-groups
#define L2E 1.44269504088896341f

typedef __attribute__((ext_vector_type(8))) _Float16 half8;
typedef __attribute__((ext_vector_type(2))) _Float16 half2v;
typedef __attribute__((ext_vector_type(4))) float f32x4;

#define MFMA16(A, B, C) __builtin_amdgcn_mfma_f32_16x16x32_f16((A), (B), (C), 0, 0, 0)

// One step, stage-major, 2 cells/lane, all register indices static.
// IBA = precomputed float[8] of (wx*x + bb) for this step (h-independent,
// issued in the pipe/read shadow by the scheduler).
#define GSTEP(IBA, IB, OB)                                                  \
    {                                                                       \
        const _Float16* hp_ = &hs[IB][sA][ab][0];                           \
        half8 a0 = *(const half8*)(hp_ + kg * 8);        /* pos 0..31  */   \
        half8 a1 = *(const half8*)(hp_ + 32 + kg * 8);   /* pos 32..63 */   \
        f32x4 acc[NT];                                                      \
        _Pragma("unroll")                                                   \
        for (int j = 0; j < NT; ++j) {                                      \
            f32x4 z = {0.0f, 0.0f, 0.0f, 0.0f};                             \
            z = MFMA16(a0, Bw[j][0], z);                                    \
            z = MFMA16(a1, Bw[j][1], z);                                    \
            acc[j] = z;                                                     \
        }                                                                   \
        float sums[NT];                                                     \
        _Pragma("unroll")                                                   \
        for (int j = 0; j < NT; ++j)                                        \
            sums[j] = acc[j][0] + acc[j][1];      /* static idx only */     \
        float sm[8], E_[8], R_[8];                                          \
        _Pragma("unroll")                                                   \
        for (int g = 0; g < 4; ++g)                                         \
            _Pragma("unroll")                                               \
            for (int l = 0; l < 2; ++l) {                                   \
                int i = g * 2 + l;                                          \
                float sel = ugp ? sums[g * 4 + 2 + l] : sums[g * 4 + l];    \
                sm[i] = sel + (IBA)[i];                                     \
            }                                                               \
        _Pragma("unroll")                                                   \
        for (int i = 0; i < 8; ++i)                                         \
            E_[i] = __builtin_amdgcn_exp2f(-sm[i]);                         \
        _Pragma("unroll")                                                   \
        for (int i = 0; i < 8; ++i)                                         \
            R_[i] = __builtin_amdgcn_rcpf(1.0f + E_[i]);                    \
        float e2_[2], r2_[2];                                               \
        _Pragma("unroll")                                                   \
        for (int l = 0; l < 2; ++l) {   /* i=R[0+l] f=R[2+l] g=R[4+l] */    \
            float vg = fmaf(2.0f, R_[4 + l], -1.0f);                        \
            cc[l] = fmaf(R_[2 + l], cc[l], R_[l] * vg);                     \
            e2_[l] = __builtin_amdgcn_exp2f(-2.0f * L2E * cc[l]);           \
        }                                                                   \
        _Pragma("unroll")                                                   \
        for (int l = 0; l < 2; ++l)                                         \
            r2_[l] = __builtin_amdgcn_rcpf(1.0f + e2_[l]);                  \
        half2v w0_, w1_;                                                    \
        _Pragma("unroll")                                                   \
        for (int l = 0; l < 2; ++l) {   /* o = R[6+l] */                    \
            hv[l] = R_[6 + l] * fmaf(2.0f, r2_[l], -1.0f);                  \
            _Float16 q0 = (_Float16)hv[l];                                  \
            w0_[l] = q0;                                                    \
            w1_[l] = (_Float16)(hv[l] - (float)q0);                         \
        }                                                                   \
        *(half2v*)&hs[OB][0][kgb][p0] = w0_;        /* split0, b32 */       \
        *(half2v*)&hs[OB][1][kgb][p0] = w1_;        /* split1, b32 */       \
    }

// Decoder step: GSTEP + in-lane fc dot + 32-lane butterfly; y -> ys, xc;
// next step's ib computed IMMEDIATELY (h-independent, hides under pipe).
#define DSTEP(T, IB, OB)                                                    \
    {                                                                       \
        GSTEP(dib, IB, OB)                                                  \
        float p = fmaf(fcw0, hv[0], fcw1 * hv[1]);                          \
        p += __shfl_xor(p, 1, 64);                                          \
        p += __shfl_xor(p, 2, 64);                                          \
        p += __shfl_xor(p, 4, 64);                                          \
        p += __shfl_xor(p, 8, 64);                                          \
        p += __shfl_xor(p, 16, 64);                                         \
        float y = p + fb;                                                   \
        if ((lane & 31) == 0) ys[kgb][T] = y;                               \
        _Pragma("unroll")                                                   \
        for (int i = 0; i < 8; ++i)                                         \
            dib[i] = fmaf(wx[i], y, bb[i]);                                 \
    }

extern "C" __global__ void __launch_bounds__(64, 1)
seq2seq_kernel(const float* __restrict__ src,
               const float* __restrict__ eWih, const float* __restrict__ eWhh,
               const float* __restrict__ eBih, const float* __restrict__ eBhh,
               const float* __restrict__ dWih, const float* __restrict__ dWhh,
               const float* __restrict__ dBih, const float* __restrict__ dBhh,
               const float* __restrict__ fcW, const float* __restrict__ fcB,
               float* __restrict__ out) {
    const int lane = threadIdx.x & 63;
    const int c    = lane & 15;          // D col / A row m
    const int kg   = lane >> 4;          // A/B k-octet; D row group
    const int kgb  = kg >> 1;            // this lane's cell batch
    const int ugp  = kg & 1;             // this lane's ugroup pair
    const int ab   = c >> 3;             // A-row m -> source batch
    const int sA   = c & 1;              // A-row m -> source h-split
    const int b0   = blockIdx.x * MB;
    const int p0   = 32 * ugp + 2 * c;   // h-write position (halves)

    // hs[buf][split][batch][72 pos(64 used; 144B stride for bank spread)]
    __shared__ __align__(16) _Float16 hs[2][2][MB][72];
    __shared__ __align__(16) float srcT[MB][SEQ];          // [batch][t]
    __shared__ __align__(16) float ys[MB][TGT];            // decoder outputs

    for (int i = lane; i < 2 * 2 * MB * 72 / 2; i += 64) ((int*)hs)[i] = 0;
    for (int i = lane; i < SEQ * MB; i += 64) {
        int e = i >> 9, t = i & 511;                       // coalesced in t
        srcT[e][t] = src[(size_t)(b0 + e) * SEQ + t];
    }
    // single wave: DS pipe is in-order; no barrier needed anywhere

    half8 Bw[NT][2];                     // [tile=(g*4+ug)][kt] fp16 weights
    float wx[8], bb[8];                  // [g*2+l] for MY 2 cells
    float cc[2] = {0.0f, 0.0f};
    float hv[2];

    auto loadW = [&](const float* Wih, const float* Whh,
                     const float* Bih, const float* Bhh) {
#pragma unroll
        for (int j = 0; j < NT; ++j) {
            const int g  = j >> 2, ug = j & 3;             // tile=(gate,ug)
            const int u  = ug * 16 + c;                    // output unit
            const bool uv = (u < HID);
            const float sc = (g == 2) ? 2.0f * L2E : L2E;  // tanh fold
            const int row = g * HID + (uv ? u : 0);        // PyTorch g*50+u
#pragma unroll
            for (int kt = 0; kt < 2; ++kt) {
                half8 s0;
#pragma unroll
                for (int jj = 0; jj < 8; ++jj) {
                    int p = kt * 32 + kg * 8 + jj;         // k position
                    int d = p >> 1, e = p & 1;
                    int us = 32 * (d >> 4) + (d & 15) + 16 * e;  // unit@pos
                    float wv = (uv && us < HID)
                             ? Whh[(size_t)row * HID + us] * sc : 0.0f;
                    s0[jj] = (_Float16)wv;
                }
                Bw[j][kt] = s0;
            }
        }
#pragma unroll
        for (int g = 0; g < 4; ++g)
#pragma unroll
            for (int l = 0; l < 2; ++l) {                  // my cells
                const int u = (2 * ugp + l) * 16 + c;
                const bool uv = (u < HID);
                const float sc = (g == 2) ? 2.0f * L2E : L2E;
                const int row = g * HID + (uv ? u : 0);
                wx[g * 2 + l] = uv ? Wih[row] * sc : 0.0f;
                bb[g * 2 + l] = uv ? (Bih[row] + Bhh[row]) * sc : 0.0f;
            }
    };

    // ---------------- encoder: 512 steps (x2 unroll, h dbuf) -------------
    loadW(eWih, eWhh, eBih, eBhh);
    for (int t = 0; t < SEQ; t += 2) {
        float2 xp = *(const float2*)&srcT[kgb][t];
        float ib0[8], ib1[8];            // h-independent: both hoisted
#pragma unroll
        for (int i = 0; i < 8; ++i) {
            ib0[i] = fmaf(wx[i], xp.x, bb[i]);
            ib1[i] = fmaf(wx[i], xp.y, bb[i]);
        }
        { GSTEP(ib0, 0, 1) }
        { GSTEP(ib1, 1, 0) }
    }
    // h(512) in buf 0; cc persists in registers

    // ---------------- decoder: 256 steps (x2 unroll) ---------------------
    loadW(dWih, dWhh, dBih, dBhh);
    const int u0f = 32 * ugp + c;        // my cell units for fc
    const int u1f = u0f + 16;
    const float fcw0 = fcW[u0f];         // u0f <= 47 < HID always
    const float fcw1 = (u1f < HID) ? fcW[u1f] : 0.0f;
    const float fb   = fcB[0];
    float dib[8];                        // decoder_input = zeros -> ib = bb
#pragma unroll
    for (int i = 0; i < 8; ++i) dib[i] = bb[i];
    for (int t = 0; t < TGT; t += 2) {
        DSTEP(t,     0, 1)
        DSTEP(t + 1, 1, 0)
    }

    // coalesced output write
    for (int i = lane; i < MB * TGT; i += 64) {
        int b = i >> 8, t = i & 255;
        out[(size_t)(b0 + b) * TGT + t] = ys[b][t];
    }
}

extern "C" void kernel_launch(void* const* d_in, const int* in_sizes, int n_in,
                              void* d_out, int out_size, void* d_ws, size_t ws_size,
                              hipStream_t stream) {
    const float* src  = (const float*)d_in[0];
    const float* eWih = (const float*)d_in[1];
    const float* eWhh = (const float*)d_in[2];
    const float* eBih = (const float*)d_in[3];
    const float* eBhh = (const float*)d_in[4];
    const float* dWih = (const float*)d_in[5];
    const float* dWhh = (const float*)d_in[6];
    const float* dBih = (const float*)d_in[7];
    const float* dBhh = (const float*)d_in[8];
    const float* fcW  = (const float*)d_in[9];
    const float* fcB  = (const float*)d_in[10];
    float* out = (float*)d_out;

    const int B = in_sizes[0] / SEQ;     // 2048
    seq2seq_kernel<<<B / MB, 64, 0, stream>>>(src, eWih, eWhh, eBih, eBhh,
                                              dWih, dWhh, dBih, dBhh,
                                              fcW, fcB, out);
}

// Round 17
// 495.618 us; speedup vs baseline: 2.6427x; 1.0118x over previous
//
#include <hip/hip_runtime.h>

// Seq2Seq LSTM (enc 512 + dec 256 steps), H=50, B=2048, in/out dim 1.
//
// Round-27: FINAL CONSOLIDATION -- r20 verbatim (session best: 468us
// dispatch / 495us dur, absmax 4.88e-4). r26's x-hoist was neutral-to-
// -1.7% -> reverted. The step is at its dependence floor; the model
// closes: 1463cy = ds round-trip ~180 + MFMA pipe 541 (32 x ~16.9cy,
// HW floor at 1 wave/SIMD) + act trans chain ~300 + issue. Wall =
// 768 x 1463cy / 2.4GHz = 468us = measured.
// Closed arcs (16 variants): parallelism (r12/r13: wall = 768 x chain,
// all configs co-resident), ILP (r16: in-order issue, +1 chain = +its
// issue count), wave co-scheduling (r23/r24/r25: weight-resident waves
// need >256 unified regs -> 1 wave/SIMD structurally), scheduling (r14
// neutral, r21 -3%, r22 SGB -23%), tiling (r18 MB=4 524us, r20 MB=2
// 468us optimum), precision (fp16 single weights = bf16-split accuracy).
//
// Structure: 1 wave = 1 block = 2 batches, no __syncthreads anywhere.
// A-rows m = b*8 + dup*2 + s (4x dup); lane (c,kg) owns cells
// (batch kg>>1, units {32*(kg&1)+c, +16}). 32 MFMA/step (16 tiles x 2 kt).
// Split combine = static sums + ternary select on ugp (rule-#20-safe).
// Grid 1024 = 1 wave/SIMD. Position perm: pos p <-> unit
// us = 32*(d>>4)+(d&15)+16*e, d=p>>1, e=p&1; producer writes one b32/split
// at p0=32*(kg&1)+2c; weights k-permuted at load. fp16 weights (rel 2^-11),
// fp16-split h (h=h0+h1), L2E folded into weights/bias (g-gate doubled ->
// tanh via sigm). Stage-major activation.
//
// Fragment maps (verified r10-r26): A[m=lane&15][k=(lane>>4)*8+j],
// B[n=lane&15][k=kt*32+(lane>>4)*8+j], D col=lane&15, row=4*(lane>>4)+reg.

#define HID 50
#define SEQ 512
#define TGT 256
#define MB  2
#define NT  16                   // 4 gates x 4 unit-groups
#define L2E 1.44269504088896341f

typedef __attribute__((ext_vector_type(8))) _Float16 half8;
typedef __attribute__((ext_vector_type(2))) _Float16 half2v;
typedef __attribute__((ext_vector_type(4))) float f32x4;

#define MFMA16(A, B, C) __builtin_amdgcn_mfma_f32_16x16x32_f16((A), (B), (C), 0, 0, 0)

// One step, stage-major, 2 cells/lane, ALL register indices static.
#define GSTEP(XV, IB, OB)                                                   \
    {                                                                       \
        const _Float16* hp_ = &hs[IB][sA][ab][0];                           \
        half8 a0 = *(const half8*)(hp_ + kg * 8);        /* pos 0..31  */   \
        half8 a1 = *(const half8*)(hp_ + 32 + kg * 8);   /* pos 32..63 */   \
        f32x4 acc[NT];                                                      \
        _Pragma("unroll")                                                   \
        for (int j = 0; j < NT; ++j) {                                      \
            f32x4 z = {0.0f, 0.0f, 0.0f, 0.0f};                             \
            z = MFMA16(a0, Bw[j][0], z);                                    \
            z = MFMA16(a1, Bw[j][1], z);                                    \
            acc[j] = z;                                                     \
        }                                                                   \
        float sums[NT];                                                     \
        _Pragma("unroll")                                                   \
        for (int j = 0; j < NT; ++j)                                        \
            sums[j] = acc[j][0] + acc[j][1];      /* static idx only */     \
        float xv_ = (XV);                                                   \
        float sm[8], E_[8], R_[8];                                          \
        _Pragma("unroll")                                                   \
        for (int g = 0; g < 4; ++g)                                         \
            _Pragma("unroll")                                               \
            for (int l = 0; l < 2; ++l) {                                   \
                int i = g * 2 + l;                                          \
                float sel = ugp ? sums[g * 4 + 2 + l] : sums[g * 4 + l];    \
                sm[i] = sel + fmaf(wx[i], xv_, bb[i]);                      \
            }                                                               \
        _Pragma("unroll")                                                   \
        for (int i = 0; i < 8; ++i)                                         \
            E_[i] = __builtin_amdgcn_exp2f(-sm[i]);                         \
        _Pragma("unroll")                                                   \
        for (int i = 0; i < 8; ++i)                                         \
            R_[i] = __builtin_amdgcn_rcpf(1.0f + E_[i]);                    \
        float e2_[2], r2_[2];                                               \
        _Pragma("unroll")                                                   \
        for (int l = 0; l < 2; ++l) {   /* i=R[0+l] f=R[2+l] g=R[4+l] */    \
            float vg = fmaf(2.0f, R_[4 + l], -1.0f);                        \
            cc[l] = fmaf(R_[2 + l], cc[l], R_[l] * vg);                     \
            e2_[l] = __builtin_amdgcn_exp2f(-2.0f * L2E * cc[l]);           \
        }                                                                   \
        _Pragma("unroll")                                                   \
        for (int l = 0; l < 2; ++l)                                         \
            r2_[l] = __builtin_amdgcn_rcpf(1.0f + e2_[l]);                  \
        half2v w0_, w1_;                                                    \
        _Pragma("unroll")                                                   \
        for (int l = 0; l < 2; ++l) {   /* o = R[6+l] */                    \
            hv[l] = R_[6 + l] * fmaf(2.0f, r2_[l], -1.0f);                  \
            _Float16 q0 = (_Float16)hv[l];                                  \
            w0_[l] = q0;                                                    \
            w1_[l] = (_Float16)(hv[l] - (float)q0);                         \
        }                                                                   \
        *(half2v*)&hs[OB][0][kgb][p0] = w0_;        /* split0, b32 */       \
        *(half2v*)&hs[OB][1][kgb][p0] = w1_;        /* split1, b32 */       \
    }

// Decoder step: GSTEP + in-lane fc dot + 32-lane butterfly; y -> ys, xc.
#define DSTEP(T, IB, OB)                                                    \
    {                                                                       \
        GSTEP(xc, IB, OB)                                                   \
        float p = fmaf(fcw0, hv[0], fcw1 * hv[1]);                          \
        p += __shfl_xor(p, 1, 64);                                          \
        p += __shfl_xor(p, 2, 64);                                          \
        p += __shfl_xor(p, 4, 64);                                          \
        p += __shfl_xor(p, 8, 64);                                          \
        p += __shfl_xor(p, 16, 64);                                         \
        float y = p + fb;                                                   \
        if ((lane & 31) == 0) ys[kgb][T] = y;                               \
        xc = y;                                                             \
    }

extern "C" __global__ void __launch_bounds__(64, 1)
seq2seq_kernel(const float* __restrict__ src,
               const float* __restrict__ eWih, const float* __restrict__ eWhh,
               const float* __restrict__ eBih, const float* __restrict__ eBhh,
               const float* __restrict__ dWih, const float* __restrict__ dWhh,
               const float* __restrict__ dBih, const float* __restrict__ dBhh,
               const float* __restrict__ fcW, const float* __restrict__ fcB,
               float* __restrict__ out) {
    const int lane = threadIdx.x & 63;
    const int c    = lane & 15;          // D col / A row m
    const int kg   = lane >> 4;          // A/B k-octet; D row group
    const int kgb  = kg >> 1;            // this lane's cell batch
    const int ugp  = kg & 1;             // this lane's ugroup pair
    const int ab   = c >> 3;             // A-row m -> source batch
    const int sA   = c & 1;              // A-row m -> source h-split
    const int b0   = blockIdx.x * MB;
    const int p0   = 32 * ugp + 2 * c;   // h-write position (halves)

    // hs[buf][split][batch][72 pos(64 used; 144B stride for bank spread)]
    __shared__ __align__(16) _Float16 hs[2][2][MB][72];
    __shared__ __align__(16) float srcT[MB][SEQ];          // [batch][t]
    __shared__ __align__(16) float ys[MB][TGT];            // decoder outputs

    for (int i = lane; i < 2 * 2 * MB * 72 / 2; i += 64) ((int*)hs)[i] = 0;
    for (int i = lane; i < SEQ * MB; i += 64) {
        int e = i >> 9, t = i & 511;                       // coalesced in t
        srcT[e][t] = src[(size_t)(b0 + e) * SEQ + t];
    }
    // single wave: DS pipe is in-order; no barrier needed anywhere

    half8 Bw[NT][2];                     // [tile=(g*4+ug)][kt] fp16 weights
    float wx[8], bb[8];                  // [g*2+l] for MY 2 cells
    float cc[2] = {0.0f, 0.0f};
    float hv[2];

    auto loadW = [&](const float* Wih, const float* Whh,
                     const float* Bih, const float* Bhh) {
#pragma unroll
        for (int j = 0; j < NT; ++j) {
            const int g  = j >> 2, ug = j & 3;             // tile=(gate,ug)
            const int u  = ug * 16 + c;                    // output unit
            const bool uv = (u < HID);
            const float sc = (g == 2) ? 2.0f * L2E : L2E;  // tanh fold
            const int row = g * HID + (uv ? u : 0);        // PyTorch g*50+u
#pragma unroll
            for (int kt = 0; kt < 2; ++kt) {
                half8 s0;
#pragma unroll
                for (int jj = 0; jj < 8; ++jj) {
                    int p = kt * 32 + kg * 8 + jj;         // k position
                    int d = p >> 1, e = p & 1;
                    int us = 32 * (d >> 4) + (d & 15) + 16 * e;  // unit@pos
                    float wv = (uv && us < HID)
                             ? Whh[(size_t)row * HID + us] * sc : 0.0f;
                    s0[jj] = (_Float16)wv;
                }
                Bw[j][kt] = s0;
            }
        }
#pragma unroll
        for (int g = 0; g < 4; ++g)
#pragma unroll
            for (int l = 0; l < 2; ++l) {                  // my cells
                const int u = (2 * ugp + l) * 16 + c;
                const bool uv = (u < HID);
                const float sc = (g == 2) ? 2.0f * L2E : L2E;
                const int row = g * HID + (uv ? u : 0);
                wx[g * 2 + l] = uv ? Wih[row] * sc : 0.0f;
                bb[g * 2 + l] = uv ? (Bih[row] + Bhh[row]) * sc : 0.0f;
            }
    };

    // ---------------- encoder: 512 steps (x2 unroll, h dbuf) -------------
    loadW(eWih, eWhh, eBih, eBhh);
    for (int t = 0; t < SEQ; t += 2) {
        float2 xp = *(const float2*)&srcT[kgb][t];
        { GSTEP(xp.x, 0, 1) }
        { GSTEP(xp.y, 1, 0) }
    }
    // h(512) in buf 0; cc persists in registers

    // ---------------- decoder: 256 steps (x2 unroll) ---------------------
    loadW(dWih, dWhh, dBih, dBhh);
    const int u0f = 32 * ugp + c;        // my cell units for fc
    const int u1f = u0f + 16;
    const float fcw0 = fcW[u0f];         // u0f <= 47 < HID always
    const float fcw1 = (u1f < HID) ? fcW[u1f] : 0.0f;
    const float fb   = fcB[0];
    float xc = 0.0f;                     // decoder_input = zeros
    for (int t = 0; t < TGT; t += 2) {
        DSTEP(t,     0, 1)
        DSTEP(t + 1, 1, 0)
    }

    // coalesced output write
    for (int i = lane; i < MB * TGT; i += 64) {
        int b = i >> 8, t = i & 255;
        out[(size_t)(b0 + b) * TGT + t] = ys[b][t];
    }
}

extern "C" void kernel_launch(void* const* d_in, const int* in_sizes, int n_in,
                              void* d_out, int out_size, void* d_ws, size_t ws_size,
                              hipStream_t stream) {
    const float* src  = (const float*)d_in[0];
    const float* eWih = (const float*)d_in[1];
    const float* eWhh = (const float*)d_in[2];
    const float* eBih = (const float*)d_in[3];
    const float* eBhh = (const float*)d_in[4];
    const float* dWih = (const float*)d_in[5];
    const float* dWhh = (const float*)d_in[6];
    const float* dBih = (const float*)d_in[7];
    const float* dBhh = (const float*)d_in[8];
    const float* fcW  = (const float*)d_in[9];
    const float* fcB  = (const float*)d_in[10];
    float* out = (float*)d_out;

    const int B = in_sizes[0] / SEQ;     // 2048
    seq2seq_kernel<<<B / MB, 64, 0, stream>>>(src, eWih, eWhh, eBih, eBhh,
                                              dWih, dWhh, dBih, dBhh,
                                              fcW, fcB, out);
}